// Round 1
// baseline (3908.799 us; speedup 1.0000x reference)
//
#include <hip/hip_runtime.h>

#define NNODES 100000
#define NEDGES 800000
#define NGRAPHS 5000
#define FN 11
#define FE 4
#define H1C 32
#define H2C 16

// agg1[n,o] = c1_bias[o] + sum_i x[n,i]*c1_root[i,o]
__global__ __launch_bounds__(256) void k_init1(const float* __restrict__ x,
    const float* __restrict__ root, const float* __restrict__ bias,
    float* __restrict__ agg1) {
  int t = blockIdx.x * 256 + threadIdx.x;
  int n = t >> 5, o = t & 31;
  if (n >= NNODES) return;
  float acc = bias[o];
  #pragma unroll
  for (int i = 0; i < FN; i++) acc += x[n * FN + i] * root[i * H1C + o];
  agg1[n * H1C + o] = acc;
}

// conv1 edge pass: 32 lanes per edge, lane owns output channel o.
__global__ __launch_bounds__(256) void k_edge1(const float* __restrict__ x,
    const int* __restrict__ ei, const float* __restrict__ ea,
    const float* __restrict__ w1, const float* __restrict__ b1,
    const float* __restrict__ w2, const float* __restrict__ b2,
    float* __restrict__ agg1) {
  int t = blockIdx.x * 256 + threadIdx.x;
  int e = t >> 5, o = t & 31;
  if (e >= NEDGES) return;
  int src = ei[e];
  int dst = ei[NEDGES + e];
  float4 a = *reinterpret_cast<const float4*>(ea + e * 4);
  // edge MLP hidden layer h[32] (uniform weights -> scalar loads)
  float h[32];
  #pragma unroll
  for (int k = 0; k < 32; k++) {
    float v = b1[k] + a.x * w1[k] + a.y * w1[32 + k] + a.z * w1[64 + k] + a.w * w1[96 + k];
    h[k] = v > 0.f ? v : 0.f;
  }
  float xs[FN];
  #pragma unroll
  for (int i = 0; i < FN; i++) xs[i] = x[src * FN + i];
  float msg = 0.f;
  #pragma unroll
  for (int i = 0; i < FN; i++) {
    float W = b2[i * H1C + o];
    #pragma unroll
    for (int k = 0; k < 32; k++) W += h[k] * w2[k * (FN * H1C) + i * H1C + o];
    msg += xs[i] * W;
  }
  atomicAdd(&agg1[dst * H1C + o], msg);
}

// h1 = relu(agg1); agg2[n,o] = c2_bias[o] + sum_i h1[n,i]*c2_root[i,o]
__global__ __launch_bounds__(256) void k_mid(const float* __restrict__ agg1,
    const float* __restrict__ root2, const float* __restrict__ bias2,
    float* __restrict__ h1, float* __restrict__ agg2) {
  int t = blockIdx.x * 256 + threadIdx.x;
  int n = t >> 4, o = t & 15;
  if (n >= NNODES) return;
  float hv[32];
  #pragma unroll
  for (int i = 0; i < 32; i++) {
    float v = agg1[n * H1C + i];
    hv[i] = v > 0.f ? v : 0.f;
  }
  h1[n * H1C + o] = hv[o];
  h1[n * H1C + o + 16] = hv[o + 16];
  float acc = bias2[o];
  #pragma unroll
  for (int i = 0; i < 32; i++) acc += hv[i] * root2[i * H2C + o];
  agg2[n * H2C + o] = acc;
}

// conv2 edge pass: 16 lanes per edge.
__global__ __launch_bounds__(256) void k_edge2(const float* __restrict__ h1,
    const int* __restrict__ ei, const float* __restrict__ ea,
    const float* __restrict__ w1, const float* __restrict__ b1,
    const float* __restrict__ w2, const float* __restrict__ b2,
    float* __restrict__ agg2) {
  int t = blockIdx.x * 256 + threadIdx.x;
  int e = t >> 4, o = t & 15;
  if (e >= NEDGES) return;
  int src = ei[e];
  int dst = ei[NEDGES + e];
  float4 a = *reinterpret_cast<const float4*>(ea + e * 4);
  float h[32];
  #pragma unroll
  for (int k = 0; k < 32; k++) {
    float v = b1[k] + a.x * w1[k] + a.y * w1[32 + k] + a.z * w1[64 + k] + a.w * w1[96 + k];
    h[k] = v > 0.f ? v : 0.f;
  }
  float hs[H1C];
  #pragma unroll
  for (int i = 0; i < H1C; i++) hs[i] = h1[src * H1C + i];
  float msg = 0.f;
  #pragma unroll
  for (int i = 0; i < H1C; i++) {
    float W = b2[i * H2C + o];
    #pragma unroll
    for (int k = 0; k < 32; k++) W += h[k] * w2[k * (H1C * H2C) + i * H2C + o];
    msg += hs[i] * W;
  }
  atomicAdd(&agg2[dst * H2C + o], msg);
}

// pooled[batch[n],o] += relu(agg2[n,o])
__global__ __launch_bounds__(256) void k_pool(const float* __restrict__ agg2,
    const int* __restrict__ batch, float* __restrict__ pooled) {
  int t = blockIdx.x * 256 + threadIdx.x;
  int n = t >> 4, o = t & 15;
  if (n >= NNODES) return;
  float v = agg2[n * H2C + o];
  v = v > 0.f ? v : 0.f;
  atomicAdd(&pooled[batch[n] * H2C + o], v);
}

// out[g] = relu(pooled[g]@fc1_w + fc1_b) @ out_w + out_b
__global__ __launch_bounds__(256) void k_head(const float* __restrict__ pooled,
    const float* __restrict__ fc1w, const float* __restrict__ fc1b,
    const float* __restrict__ outw, const float* __restrict__ outb,
    float* __restrict__ out) {
  int g = blockIdx.x * 256 + threadIdx.x;
  if (g >= NGRAPHS) return;
  float p[H2C];
  #pragma unroll
  for (int i = 0; i < H2C; i++) p[i] = pooled[g * H2C + i];
  float acc = outb[0];
  #pragma unroll
  for (int o = 0; o < H1C; o++) {
    float v = fc1b[o];
    #pragma unroll
    for (int i = 0; i < H2C; i++) v += p[i] * fc1w[i * H1C + o];
    v = v > 0.f ? v : 0.f;
    acc += v * outw[o];
  }
  out[g] = acc;
}

extern "C" void kernel_launch(void* const* d_in, const int* in_sizes, int n_in,
                              void* d_out, int out_size, void* d_ws, size_t ws_size,
                              hipStream_t stream) {
  const float* x      = (const float*)d_in[0];
  const int*   ei     = (const int*)d_in[1];
  const float* ea     = (const float*)d_in[2];
  const int*   batch  = (const int*)d_in[3];
  const float* c1w1   = (const float*)d_in[4];
  const float* c1b1   = (const float*)d_in[5];
  const float* c1w2   = (const float*)d_in[6];
  const float* c1b2   = (const float*)d_in[7];
  const float* c1root = (const float*)d_in[8];
  const float* c1bias = (const float*)d_in[9];
  const float* c2w1   = (const float*)d_in[10];
  const float* c2b1   = (const float*)d_in[11];
  const float* c2w2   = (const float*)d_in[12];
  const float* c2b2   = (const float*)d_in[13];
  const float* c2root = (const float*)d_in[14];
  const float* c2bias = (const float*)d_in[15];
  const float* fc1w   = (const float*)d_in[16];
  const float* fc1b   = (const float*)d_in[17];
  const float* outw   = (const float*)d_in[18];
  const float* outb   = (const float*)d_in[19];
  float* out = (float*)d_out;

  float* agg1   = (float*)d_ws;                 // 100000*32
  float* h1     = agg1 + NNODES * H1C;          // 100000*32
  float* agg2   = h1 + NNODES * H1C;            // 100000*16
  float* pooled = agg2 + NNODES * H2C;          // 5000*16

  hipMemsetAsync(pooled, 0, NGRAPHS * H2C * sizeof(float), stream);

  k_init1<<<(NNODES * H1C + 255) / 256, 256, 0, stream>>>(x, c1root, c1bias, agg1);
  k_edge1<<<(NEDGES * 32) / 256, 256, 0, stream>>>(x, ei, ea, c1w1, c1b1, c1w2, c1b2, agg1);
  k_mid<<<(NNODES * H2C + 255) / 256, 256, 0, stream>>>(agg1, c2root, c2bias, h1, agg2);
  k_edge2<<<(NEDGES * 16) / 256, 256, 0, stream>>>(h1, ei, ea, c2w1, c2b1, c2w2, c2b2, agg2);
  k_pool<<<(NNODES * H2C + 255) / 256, 256, 0, stream>>>(agg2, batch, pooled);
  k_head<<<(NGRAPHS + 255) / 256, 256, 0, stream>>>(pooled, fc1w, fc1b, outw, outb, out);
}

// Round 2
// 2417.316 us; speedup vs baseline: 1.6170x; 1.6170x over previous
//
#include <hip/hip_runtime.h>

#define NNODES 100000
#define NEDGES 800000
#define NGRAPHS 5000
#define FN 11
#define FE 4
#define H1C 32
#define H2C 16

// agg1[n,o] = c1_bias[o] + sum_i x[n,i]*c1_root[i,o]
__global__ __launch_bounds__(256) void k_init1(const float* __restrict__ x,
    const float* __restrict__ root, const float* __restrict__ bias,
    float* __restrict__ agg1) {
  int t = blockIdx.x * 256 + threadIdx.x;
  int n = t >> 5, o = t & 31;
  if (n >= NNODES) return;
  float acc = bias[o];
  #pragma unroll
  for (int i = 0; i < FN; i++) acc += x[n * FN + i] * root[i * H1C + o];
  agg1[n * H1C + o] = acc;
}

// conv1 edge pass: ONE THREAD PER EDGE. All weight indices are wave-uniform
// -> scalar (SGPR) loads; VALU does the FMAs with an SGPR operand.
__global__ __launch_bounds__(256) void k_edge1(const float* __restrict__ x,
    const int* __restrict__ ei, const float* __restrict__ ea,
    const float* __restrict__ w1, const float* __restrict__ b1,
    const float* __restrict__ w2, const float* __restrict__ b2,
    float* __restrict__ agg1) {
  int e = blockIdx.x * 256 + threadIdx.x;
  if (e >= NEDGES) return;
  int src = ei[e];
  int dst = ei[NEDGES + e];
  float4 a = *reinterpret_cast<const float4*>(ea + e * 4);
  float h[32];
  #pragma unroll
  for (int k = 0; k < 32; k++) {
    float v = b1[k] + a.x * w1[k] + a.y * w1[32 + k] + a.z * w1[64 + k] + a.w * w1[96 + k];
    h[k] = v > 0.f ? v : 0.f;
  }
  float xs[FN];
  #pragma unroll
  for (int i = 0; i < FN; i++) xs[i] = x[src * FN + i];
  float acc[H1C];
  #pragma unroll
  for (int o = 0; o < H1C; o++) acc[o] = 0.f;
  // bias-of-W part: acc[o] += sum_i xs[i]*b2[i,o]
  #pragma unroll
  for (int i = 0; i < FN; i++) {
    #pragma unroll
    for (int o = 0; o < H1C; o++) acc[o] += xs[i] * b2[i * H1C + o];
  }
  // main: acc[o] += sum_k sum_i (h[k]*xs[i]) * w2[k,i,o]
  #pragma unroll 1
  for (int k = 0; k < 32; k++) {
    float hk = h[k];
    const float* w2k = w2 + k * (FN * H1C);
    #pragma unroll
    for (int i = 0; i < FN; i++) {
      float hx = hk * xs[i];
      #pragma unroll
      for (int o = 0; o < H1C; o++) acc[o] += hx * w2k[i * H1C + o];
    }
  }
  #pragma unroll
  for (int o = 0; o < H1C; o++) atomicAdd(&agg1[dst * H1C + o], acc[o]);
}

// h1 = relu(agg1); agg2[n,o] = c2_bias[o] + sum_i h1[n,i]*c2_root[i,o]
__global__ __launch_bounds__(256) void k_mid(const float* __restrict__ agg1,
    const float* __restrict__ root2, const float* __restrict__ bias2,
    float* __restrict__ h1, float* __restrict__ agg2) {
  int t = blockIdx.x * 256 + threadIdx.x;
  int n = t >> 4, o = t & 15;
  if (n >= NNODES) return;
  float hv[32];
  #pragma unroll
  for (int i = 0; i < 32; i++) {
    float v = agg1[n * H1C + i];
    hv[i] = v > 0.f ? v : 0.f;
  }
  h1[n * H1C + o] = hv[o];
  h1[n * H1C + o + 16] = hv[o + 16];
  float acc = bias2[o];
  #pragma unroll
  for (int i = 0; i < 32; i++) acc += hv[i] * root2[i * H2C + o];
  agg2[n * H2C + o] = acc;
}

// conv2 edge pass: one thread per edge, uniform weight access.
__global__ __launch_bounds__(256) void k_edge2(const float* __restrict__ h1,
    const int* __restrict__ ei, const float* __restrict__ ea,
    const float* __restrict__ w1, const float* __restrict__ b1,
    const float* __restrict__ w2, const float* __restrict__ b2,
    float* __restrict__ agg2) {
  int e = blockIdx.x * 256 + threadIdx.x;
  if (e >= NEDGES) return;
  int src = ei[e];
  int dst = ei[NEDGES + e];
  float4 a = *reinterpret_cast<const float4*>(ea + e * 4);
  float h[32];
  #pragma unroll
  for (int k = 0; k < 32; k++) {
    float v = b1[k] + a.x * w1[k] + a.y * w1[32 + k] + a.z * w1[64 + k] + a.w * w1[96 + k];
    h[k] = v > 0.f ? v : 0.f;
  }
  float hs[H1C];
  #pragma unroll
  for (int i = 0; i < H1C; i++) hs[i] = h1[src * H1C + i];
  float acc[H2C];
  #pragma unroll
  for (int o = 0; o < H2C; o++) acc[o] = 0.f;
  #pragma unroll
  for (int i = 0; i < H1C; i++) {
    #pragma unroll
    for (int o = 0; o < H2C; o++) acc[o] += hs[i] * b2[i * H2C + o];
  }
  #pragma unroll 1
  for (int k = 0; k < 32; k++) {
    float hk = h[k];
    const float* w2k = w2 + k * (H1C * H2C);
    #pragma unroll
    for (int i = 0; i < H1C; i++) {
      float hx = hk * hs[i];
      #pragma unroll
      for (int o = 0; o < H2C; o++) acc[o] += hx * w2k[i * H2C + o];
    }
  }
  #pragma unroll
  for (int o = 0; o < H2C; o++) atomicAdd(&agg2[dst * H2C + o], acc[o]);
}

// pooled[batch[n],o] += relu(agg2[n,o])
__global__ __launch_bounds__(256) void k_pool(const float* __restrict__ agg2,
    const int* __restrict__ batch, float* __restrict__ pooled) {
  int t = blockIdx.x * 256 + threadIdx.x;
  int n = t >> 4, o = t & 15;
  if (n >= NNODES) return;
  float v = agg2[n * H2C + o];
  v = v > 0.f ? v : 0.f;
  atomicAdd(&pooled[batch[n] * H2C + o], v);
}

// out[g] = relu(pooled[g]@fc1_w + fc1_b) @ out_w + out_b
__global__ __launch_bounds__(256) void k_head(const float* __restrict__ pooled,
    const float* __restrict__ fc1w, const float* __restrict__ fc1b,
    const float* __restrict__ outw, const float* __restrict__ outb,
    float* __restrict__ out) {
  int g = blockIdx.x * 256 + threadIdx.x;
  if (g >= NGRAPHS) return;
  float p[H2C];
  #pragma unroll
  for (int i = 0; i < H2C; i++) p[i] = pooled[g * H2C + i];
  float acc = outb[0];
  #pragma unroll
  for (int o = 0; o < H1C; o++) {
    float v = fc1b[o];
    #pragma unroll
    for (int i = 0; i < H2C; i++) v += p[i] * fc1w[i * H1C + o];
    v = v > 0.f ? v : 0.f;
    acc += v * outw[o];
  }
  out[g] = acc;
}

extern "C" void kernel_launch(void* const* d_in, const int* in_sizes, int n_in,
                              void* d_out, int out_size, void* d_ws, size_t ws_size,
                              hipStream_t stream) {
  const float* x      = (const float*)d_in[0];
  const int*   ei     = (const int*)d_in[1];
  const float* ea     = (const float*)d_in[2];
  const int*   batch  = (const int*)d_in[3];
  const float* c1w1   = (const float*)d_in[4];
  const float* c1b1   = (const float*)d_in[5];
  const float* c1w2   = (const float*)d_in[6];
  const float* c1b2   = (const float*)d_in[7];
  const float* c1root = (const float*)d_in[8];
  const float* c1bias = (const float*)d_in[9];
  const float* c2w1   = (const float*)d_in[10];
  const float* c2b1   = (const float*)d_in[11];
  const float* c2w2   = (const float*)d_in[12];
  const float* c2b2   = (const float*)d_in[13];
  const float* c2root = (const float*)d_in[14];
  const float* c2bias = (const float*)d_in[15];
  const float* fc1w   = (const float*)d_in[16];
  const float* fc1b   = (const float*)d_in[17];
  const float* outw   = (const float*)d_in[18];
  const float* outb   = (const float*)d_in[19];
  float* out = (float*)d_out;

  float* agg1   = (float*)d_ws;                 // 100000*32
  float* h1     = agg1 + NNODES * H1C;          // 100000*32
  float* agg2   = h1 + NNODES * H1C;            // 100000*16
  float* pooled = agg2 + NNODES * H2C;          // 5000*16

  hipMemsetAsync(pooled, 0, NGRAPHS * H2C * sizeof(float), stream);

  k_init1<<<(NNODES * H1C + 255) / 256, 256, 0, stream>>>(x, c1root, c1bias, agg1);
  k_edge1<<<(NEDGES + 255) / 256, 256, 0, stream>>>(x, ei, ea, c1w1, c1b1, c1w2, c1b2, agg1);
  k_mid<<<(NNODES * H2C + 255) / 256, 256, 0, stream>>>(agg1, c2root, c2bias, h1, agg2);
  k_edge2<<<(NEDGES + 255) / 256, 256, 0, stream>>>(h1, ei, ea, c2w1, c2b1, c2w2, c2b2, agg2);
  k_pool<<<(NNODES * H2C + 255) / 256, 256, 0, stream>>>(agg2, batch, pooled);
  k_head<<<(NGRAPHS + 255) / 256, 256, 0, stream>>>(pooled, fc1w, fc1b, outw, outb, out);
}

// Round 3
// 912.228 us; speedup vs baseline: 4.2849x; 2.6499x over previous
//
#include <hip/hip_runtime.h>

#define NNODES 100000
#define NEDGES 800000
#define NGRAPHS 5000
#define FN 11
#define FE 4
#define H1C 32
#define H2C 16

// agg1[n,o] = c1_bias[o] + sum_i x[n,i]*c1_root[i,o]
__global__ __launch_bounds__(256) void k_init1(const float* __restrict__ x,
    const float* __restrict__ root, const float* __restrict__ bias,
    float* __restrict__ agg1) {
  int t = blockIdx.x * 256 + threadIdx.x;
  int n = t >> 5, o = t & 31;
  if (n >= NNODES) return;
  float acc = bias[o];
  #pragma unroll
  for (int i = 0; i < FN; i++) acc += x[n * FN + i] * root[i * H1C + o];
  agg1[n * H1C + o] = acc;
}

// conv1 edge pass: thread-per-edge compute (scalar weight operands),
// LDS transpose, then lane-per-channel coalesced atomics.
__global__ __launch_bounds__(256) void k_edge1(const float* __restrict__ x,
    const int* __restrict__ ei, const float* __restrict__ ea,
    const float* __restrict__ w1, const float* __restrict__ b1,
    const float* __restrict__ w2, const float* __restrict__ b2,
    float* __restrict__ agg1) {
  __shared__ float s_acc[256][H1C + 1];
  __shared__ int s_dst[256];
  int tid = threadIdx.x;
  int e = blockIdx.x * 256 + tid;   // NEDGES % 256 == 0, no guard needed
  int src = ei[e];
  s_dst[tid] = ei[NEDGES + e];
  float4 a = *reinterpret_cast<const float4*>(ea + e * 4);
  float h[32];
  #pragma unroll
  for (int k = 0; k < 32; k++) {
    float v = b1[k] + a.x * w1[k] + a.y * w1[32 + k] + a.z * w1[64 + k] + a.w * w1[96 + k];
    h[k] = v > 0.f ? v : 0.f;
  }
  float xs[FN];
  #pragma unroll
  for (int i = 0; i < FN; i++) xs[i] = x[src * FN + i];
  float acc[H1C];
  #pragma unroll
  for (int o = 0; o < H1C; o++) acc[o] = 0.f;
  #pragma unroll
  for (int i = 0; i < FN; i++) {
    #pragma unroll
    for (int o = 0; o < H1C; o++) acc[o] += xs[i] * b2[i * H1C + o];
  }
  #pragma unroll 1
  for (int k = 0; k < 32; k++) {
    float hk = h[k];
    const float* w2k = w2 + k * (FN * H1C);
    #pragma unroll
    for (int i = 0; i < FN; i++) {
      float hx = hk * xs[i];
      #pragma unroll
      for (int o = 0; o < H1C; o++) acc[o] += hx * w2k[i * H1C + o];
    }
  }
  #pragma unroll
  for (int o = 0; o < H1C; o++) s_acc[tid][o] = acc[o];
  __syncthreads();
  // 32 passes; each pass: 8 edges x 32 channels across the block.
  int o = tid & 31;
  int esub = tid >> 5;   // 0..7
  #pragma unroll 1
  for (int p = 0; p < 32; p++) {
    int el = p * 8 + esub;
    atomicAdd(&agg1[s_dst[el] * H1C + o], s_acc[el][o]);
  }
}

// h1 = relu(agg1); agg2[n,o] = c2_bias[o] + sum_i h1[n,i]*c2_root[i,o]
__global__ __launch_bounds__(256) void k_mid(const float* __restrict__ agg1,
    const float* __restrict__ root2, const float* __restrict__ bias2,
    float* __restrict__ h1, float* __restrict__ agg2) {
  int t = blockIdx.x * 256 + threadIdx.x;
  int n = t >> 4, o = t & 15;
  if (n >= NNODES) return;
  float hv[32];
  #pragma unroll
  for (int i = 0; i < 32; i++) {
    float v = agg1[n * H1C + i];
    hv[i] = v > 0.f ? v : 0.f;
  }
  h1[n * H1C + o] = hv[o];
  h1[n * H1C + o + 16] = hv[o + 16];
  float acc = bias2[o];
  #pragma unroll
  for (int i = 0; i < 32; i++) acc += hv[i] * root2[i * H2C + o];
  agg2[n * H2C + o] = acc;
}

// conv2 edge pass: thread-per-edge + LDS transpose + coalesced atomics.
__global__ __launch_bounds__(256) void k_edge2(const float* __restrict__ h1,
    const int* __restrict__ ei, const float* __restrict__ ea,
    const float* __restrict__ w1, const float* __restrict__ b1,
    const float* __restrict__ w2, const float* __restrict__ b2,
    float* __restrict__ agg2) {
  __shared__ float s_acc[256][H2C + 1];
  __shared__ int s_dst[256];
  int tid = threadIdx.x;
  int e = blockIdx.x * 256 + tid;
  int src = ei[e];
  s_dst[tid] = ei[NEDGES + e];
  float4 a = *reinterpret_cast<const float4*>(ea + e * 4);
  float h[32];
  #pragma unroll
  for (int k = 0; k < 32; k++) {
    float v = b1[k] + a.x * w1[k] + a.y * w1[32 + k] + a.z * w1[64 + k] + a.w * w1[96 + k];
    h[k] = v > 0.f ? v : 0.f;
  }
  float hs[H1C];
  #pragma unroll
  for (int i = 0; i < H1C; i++) hs[i] = h1[src * H1C + i];
  float acc[H2C];
  #pragma unroll
  for (int o = 0; o < H2C; o++) acc[o] = 0.f;
  #pragma unroll
  for (int i = 0; i < H1C; i++) {
    #pragma unroll
    for (int o = 0; o < H2C; o++) acc[o] += hs[i] * b2[i * H2C + o];
  }
  #pragma unroll 1
  for (int k = 0; k < 32; k++) {
    float hk = h[k];
    const float* w2k = w2 + k * (H1C * H2C);
    #pragma unroll
    for (int i = 0; i < H1C; i++) {
      float hx = hk * hs[i];
      #pragma unroll
      for (int o = 0; o < H2C; o++) acc[o] += hx * w2k[i * H2C + o];
    }
  }
  #pragma unroll
  for (int o = 0; o < H2C; o++) s_acc[tid][o] = acc[o];
  __syncthreads();
  // 16 passes; each pass: 16 edges x 16 channels across the block.
  int o = tid & 15;
  int esub = tid >> 4;   // 0..15
  #pragma unroll 1
  for (int p = 0; p < 16; p++) {
    int el = p * 16 + esub;
    atomicAdd(&agg2[s_dst[el] * H2C + o], s_acc[el][o]);
  }
}

// pooled[batch[n],o] += relu(agg2[n,o])
__global__ __launch_bounds__(256) void k_pool(const float* __restrict__ agg2,
    const int* __restrict__ batch, float* __restrict__ pooled) {
  int t = blockIdx.x * 256 + threadIdx.x;
  int n = t >> 4, o = t & 15;
  if (n >= NNODES) return;
  float v = agg2[n * H2C + o];
  v = v > 0.f ? v : 0.f;
  atomicAdd(&pooled[batch[n] * H2C + o], v);
}

// out[g] = relu(pooled[g]@fc1_w + fc1_b) @ out_w + out_b
__global__ __launch_bounds__(256) void k_head(const float* __restrict__ pooled,
    const float* __restrict__ fc1w, const float* __restrict__ fc1b,
    const float* __restrict__ outw, const float* __restrict__ outb,
    float* __restrict__ out) {
  int g = blockIdx.x * 256 + threadIdx.x;
  if (g >= NGRAPHS) return;
  float p[H2C];
  #pragma unroll
  for (int i = 0; i < H2C; i++) p[i] = pooled[g * H2C + i];
  float acc = outb[0];
  #pragma unroll
  for (int o = 0; o < H1C; o++) {
    float v = fc1b[o];
    #pragma unroll
    for (int i = 0; i < H2C; i++) v += p[i] * fc1w[i * H1C + o];
    v = v > 0.f ? v : 0.f;
    acc += v * outw[o];
  }
  out[g] = acc;
}

extern "C" void kernel_launch(void* const* d_in, const int* in_sizes, int n_in,
                              void* d_out, int out_size, void* d_ws, size_t ws_size,
                              hipStream_t stream) {
  const float* x      = (const float*)d_in[0];
  const int*   ei     = (const int*)d_in[1];
  const float* ea     = (const float*)d_in[2];
  const int*   batch  = (const int*)d_in[3];
  const float* c1w1   = (const float*)d_in[4];
  const float* c1b1   = (const float*)d_in[5];
  const float* c1w2   = (const float*)d_in[6];
  const float* c1b2   = (const float*)d_in[7];
  const float* c1root = (const float*)d_in[8];
  const float* c1bias = (const float*)d_in[9];
  const float* c2w1   = (const float*)d_in[10];
  const float* c2b1   = (const float*)d_in[11];
  const float* c2w2   = (const float*)d_in[12];
  const float* c2b2   = (const float*)d_in[13];
  const float* c2root = (const float*)d_in[14];
  const float* c2bias = (const float*)d_in[15];
  const float* fc1w   = (const float*)d_in[16];
  const float* fc1b   = (const float*)d_in[17];
  const float* outw   = (const float*)d_in[18];
  const float* outb   = (const float*)d_in[19];
  float* out = (float*)d_out;

  float* agg1   = (float*)d_ws;                 // 100000*32
  float* h1     = agg1 + NNODES * H1C;          // 100000*32
  float* agg2   = h1 + NNODES * H1C;            // 100000*16
  float* pooled = agg2 + NNODES * H2C;          // 5000*16

  hipMemsetAsync(pooled, 0, NGRAPHS * H2C * sizeof(float), stream);

  k_init1<<<(NNODES * H1C + 255) / 256, 256, 0, stream>>>(x, c1root, c1bias, agg1);
  k_edge1<<<NEDGES / 256, 256, 0, stream>>>(x, ei, ea, c1w1, c1b1, c1w2, c1b2, agg1);
  k_mid<<<(NNODES * H2C + 255) / 256, 256, 0, stream>>>(agg1, c2root, c2bias, h1, agg2);
  k_edge2<<<NEDGES / 256, 256, 0, stream>>>(h1, ei, ea, c2w1, c2b1, c2w2, c2b2, agg2);
  k_pool<<<(NNODES * H2C + 255) / 256, 256, 0, stream>>>(agg2, batch, pooled);
  k_head<<<(NGRAPHS + 255) / 256, 256, 0, stream>>>(pooled, fc1w, fc1b, outw, outb, out);
}

// Round 4
// 409.924 us; speedup vs baseline: 9.5354x; 2.2254x over previous
//
#include <hip/hip_runtime.h>

#define NNODES 100000
#define NEDGES 800000
#define NGRAPHS 5000
#define FN 11
#define FE 4
#define H1C 32
#define H2C 16

typedef __bf16 bf16x8 __attribute__((ext_vector_type(8)));
typedef float f32x4 __attribute__((ext_vector_type(4)));

// agg1[n,o] = c1_bias[o] + sum_i x[n,i]*c1_root[i,o]
__global__ __launch_bounds__(256) void k_init1(const float* __restrict__ x,
    const float* __restrict__ root, const float* __restrict__ bias,
    float* __restrict__ agg1) {
  int t = blockIdx.x * 256 + threadIdx.x;
  int n = t >> 5, o = t & 31;
  if (n >= NNODES) return;
  float acc = bias[o];
  #pragma unroll
  for (int i = 0; i < FN; i++) acc += x[n * FN + i] * root[i * H1C + o];
  agg1[n * H1C + o] = acc;
}

// conv1 edge pass: thread-per-edge fp32 (unchanged from round 3).
__global__ __launch_bounds__(256) void k_edge1(const float* __restrict__ x,
    const int* __restrict__ ei, const float* __restrict__ ea,
    const float* __restrict__ w1, const float* __restrict__ b1,
    const float* __restrict__ w2, const float* __restrict__ b2,
    float* __restrict__ agg1) {
  __shared__ float s_acc[256][H1C + 1];
  __shared__ int s_dst[256];
  int tid = threadIdx.x;
  int e = blockIdx.x * 256 + tid;
  int src = ei[e];
  s_dst[tid] = ei[NEDGES + e];
  float4 a = *reinterpret_cast<const float4*>(ea + e * 4);
  float h[32];
  #pragma unroll
  for (int k = 0; k < 32; k++) {
    float v = b1[k] + a.x * w1[k] + a.y * w1[32 + k] + a.z * w1[64 + k] + a.w * w1[96 + k];
    h[k] = v > 0.f ? v : 0.f;
  }
  float xs[FN];
  #pragma unroll
  for (int i = 0; i < FN; i++) xs[i] = x[src * FN + i];
  float acc[H1C];
  #pragma unroll
  for (int o = 0; o < H1C; o++) acc[o] = 0.f;
  #pragma unroll
  for (int i = 0; i < FN; i++) {
    #pragma unroll
    for (int o = 0; o < H1C; o++) acc[o] += xs[i] * b2[i * H1C + o];
  }
  #pragma unroll 1
  for (int k = 0; k < 32; k++) {
    float hk = h[k];
    const float* w2k = w2 + k * (FN * H1C);
    #pragma unroll
    for (int i = 0; i < FN; i++) {
      float hx = hk * xs[i];
      #pragma unroll
      for (int o = 0; o < H1C; o++) acc[o] += hx * w2k[i * H1C + o];
    }
  }
  #pragma unroll
  for (int o = 0; o < H1C; o++) s_acc[tid][o] = acc[o];
  __syncthreads();
  int o = tid & 31;
  int esub = tid >> 5;
  #pragma unroll 1
  for (int p = 0; p < 32; p++) {
    int el = p * 8 + esub;
    atomicAdd(&agg1[s_dst[el] * H1C + o], s_acc[el][o]);
  }
}

// h1b = bf16(relu(agg1)); agg2[n,o] = c2_bias[o] + sum_i relu(agg1)[n,i]*c2_root[i,o]
__global__ __launch_bounds__(256) void k_mid(const float* __restrict__ agg1,
    const float* __restrict__ root2, const float* __restrict__ bias2,
    __bf16* __restrict__ h1b, float* __restrict__ agg2) {
  int t = blockIdx.x * 256 + threadIdx.x;
  int n = t >> 4, o = t & 15;
  if (n >= NNODES) return;
  float hv[32];
  #pragma unroll
  for (int i = 0; i < 32; i++) {
    float v = agg1[n * H1C + i];
    hv[i] = v > 0.f ? v : 0.f;
  }
  h1b[n * H1C + o] = (__bf16)hv[o];
  h1b[n * H1C + o + 16] = (__bf16)hv[o + 16];
  float acc = bias2[o];
  #pragma unroll
  for (int i = 0; i < 32; i++) acc += hv[i] * root2[i * H2C + o];
  agg2[n * H2C + o] = acc;
}

// Build pre-swizzled bf16 B-fragments for conv2 MFMA:
// B2s[(kk*64+l)*8+j] = w2[kglob= kk*32 + (l>>4)*8+j ][ o = l&15 ]
__global__ __launch_bounds__(256) void k_prepB2(const float* __restrict__ w2,
    __bf16* __restrict__ B2s) {
  int t = blockIdx.x * 256 + threadIdx.x;
  if (t >= 32 * 64 * 8) return;
  int kk = t >> 9;
  int l = (t >> 3) & 63;
  int j = t & 7;
  int i = (l >> 4) * 8 + j;   // 0..31
  int o = l & 15;
  B2s[t] = (__bf16)w2[(kk * 32 + i) * H2C + o];
}

// conv2 edge pass via MFMA: msg[e,:] = z[e,:]@W2, z[e,k*32+i]=h[e,k]*hs[e,i].
// A-frag for step kk: a[j] = h[e,kk] * hs[e,(l>>4)*8+j]  (hs slice loaded once).
__global__ __launch_bounds__(256) void k_edge2_mfma(
    const __bf16* __restrict__ h1b, const int* __restrict__ ei,
    const float* __restrict__ ea, const float* __restrict__ w1,
    const float* __restrict__ b1, const __bf16* __restrict__ B2s,
    float* __restrict__ agg2) {
  __shared__ __bf16 Bl[32 * 64 * 8];     // 32 KB: B-frags, [kk][lane][8]
  __shared__ float h_lds[256][33];       // 33.8 KB (pad 33 -> conflict-free)
  __shared__ int s_src[256];
  __shared__ int s_dst[256];
  int tid = threadIdx.x;
  // cooperative copy of pre-swizzled B (32 KB) into LDS
  {
    const int4* s = (const int4*)B2s;
    int4* d = (int4*)Bl;
    #pragma unroll
    for (int q = 0; q < 8; q++) d[tid * 8 + q] = s[tid * 8 + q];
  }
  int e = blockIdx.x * 256 + tid;   // NEDGES % 256 == 0
  s_src[tid] = ei[e];
  s_dst[tid] = ei[NEDGES + e];
  float4 a4 = *reinterpret_cast<const float4*>(ea + e * 4);
  #pragma unroll
  for (int k = 0; k < 32; k++) {
    float v = b1[k] + a4.x * w1[k] + a4.y * w1[32 + k] + a4.z * w1[64 + k] + a4.w * w1[96 + k];
    h_lds[tid][k] = v > 0.f ? v : 0.f;
  }
  __syncthreads();
  int lane = tid & 63;
  int w = tid >> 6;
  int halfk = lane >> 4;          // 0..3  -> k-slice base halfk*8
  int er = lane & 15;             // edge-in-group / output col o
  #pragma unroll 1
  for (int g = 0; g < 4; g++) {
    int eb = w * 64 + g * 16;     // this wave's 16-edge group
    int el = eb + er;
    int sn = s_src[el];
    bf16x8 hsb = *reinterpret_cast<const bf16x8*>(h1b + sn * H1C + halfk * 8);
    float hsf[8];
    #pragma unroll
    for (int j = 0; j < 8; j++) hsf[j] = (float)hsb[j];
    f32x4 acc = {0.f, 0.f, 0.f, 0.f};
    #pragma unroll
    for (int kk = 0; kk < 32; kk++) {
      float hscal = h_lds[el][kk];
      bf16x8 bfrag = *reinterpret_cast<const bf16x8*>(Bl + (kk * 64 + lane) * 8);
      bf16x8 afrag;
      #pragma unroll
      for (int j = 0; j < 8; j++) afrag[j] = (__bf16)(hscal * hsf[j]);
      acc = __builtin_amdgcn_mfma_f32_16x16x32_bf16(afrag, bfrag, acc, 0, 0, 0);
    }
    // C layout: col o = lane&15, row = (lane>>4)*4 + r  (edge within group)
    #pragma unroll
    for (int r = 0; r < 4; r++) {
      int row = halfk * 4 + r;
      int d = s_dst[eb + row];
      atomicAdd(&agg2[d * H2C + er], acc[r]);
    }
  }
}

// pooled[batch[n],o] += relu(agg2[n,o])
__global__ __launch_bounds__(256) void k_pool(const float* __restrict__ agg2,
    const int* __restrict__ batch, float* __restrict__ pooled) {
  int t = blockIdx.x * 256 + threadIdx.x;
  int n = t >> 4, o = t & 15;
  if (n >= NNODES) return;
  float v = agg2[n * H2C + o];
  v = v > 0.f ? v : 0.f;
  atomicAdd(&pooled[batch[n] * H2C + o], v);
}

// out[g] = relu(pooled[g]@fc1_w + fc1_b) @ out_w + out_b
__global__ __launch_bounds__(256) void k_head(const float* __restrict__ pooled,
    const float* __restrict__ fc1w, const float* __restrict__ fc1b,
    const float* __restrict__ outw, const float* __restrict__ outb,
    float* __restrict__ out) {
  int g = blockIdx.x * 256 + threadIdx.x;
  if (g >= NGRAPHS) return;
  float p[H2C];
  #pragma unroll
  for (int i = 0; i < H2C; i++) p[i] = pooled[g * H2C + i];
  float acc = outb[0];
  #pragma unroll
  for (int o = 0; o < H1C; o++) {
    float v = fc1b[o];
    #pragma unroll
    for (int i = 0; i < H2C; i++) v += p[i] * fc1w[i * H1C + o];
    v = v > 0.f ? v : 0.f;
    acc += v * outw[o];
  }
  out[g] = acc;
}

extern "C" void kernel_launch(void* const* d_in, const int* in_sizes, int n_in,
                              void* d_out, int out_size, void* d_ws, size_t ws_size,
                              hipStream_t stream) {
  const float* x      = (const float*)d_in[0];
  const int*   ei     = (const int*)d_in[1];
  const float* ea     = (const float*)d_in[2];
  const int*   batch  = (const int*)d_in[3];
  const float* c1w1   = (const float*)d_in[4];
  const float* c1b1   = (const float*)d_in[5];
  const float* c1w2   = (const float*)d_in[6];
  const float* c1b2   = (const float*)d_in[7];
  const float* c1root = (const float*)d_in[8];
  const float* c1bias = (const float*)d_in[9];
  const float* c2w1   = (const float*)d_in[10];
  const float* c2b1   = (const float*)d_in[11];
  const float* c2w2   = (const float*)d_in[12];
  const float* c2b2   = (const float*)d_in[13];
  const float* c2root = (const float*)d_in[14];
  const float* c2bias = (const float*)d_in[15];
  const float* fc1w   = (const float*)d_in[16];
  const float* fc1b   = (const float*)d_in[17];
  const float* outw   = (const float*)d_in[18];
  const float* outb   = (const float*)d_in[19];
  float* out = (float*)d_out;

  float*   agg1   = (float*)d_ws;                       // 100000*32 f32
  __bf16*  h1b    = (__bf16*)(agg1 + NNODES * H1C);     // 100000*32 bf16
  float*   agg2   = (float*)(h1b + NNODES * H1C);       // 100000*16 f32
  float*   pooled = agg2 + NNODES * H2C;                // 5000*16 f32
  __bf16*  B2s    = (__bf16*)(pooled + NGRAPHS * H2C);  // 16384 bf16

  hipMemsetAsync(pooled, 0, NGRAPHS * H2C * sizeof(float), stream);

  k_init1<<<(NNODES * H1C + 255) / 256, 256, 0, stream>>>(x, c1root, c1bias, agg1);
  k_prepB2<<<64, 256, 0, stream>>>(c2w2, B2s);
  k_edge1<<<NEDGES / 256, 256, 0, stream>>>(x, ei, ea, c1w1, c1b1, c1w2, c1b2, agg1);
  k_mid<<<(NNODES * H2C + 255) / 256, 256, 0, stream>>>(agg1, c2root, c2bias, h1b, agg2);
  k_edge2_mfma<<<NEDGES / 256, 256, 0, stream>>>(h1b, ei, ea, c2w1, c2b1, B2s, agg2);
  k_pool<<<(NNODES * H2C + 255) / 256, 256, 0, stream>>>(agg2, batch, pooled);
  k_head<<<(NGRAPHS + 255) / 256, 256, 0, stream>>>(pooled, fc1w, fc1b, outw, outb, out);
}

// Round 5
// 272.579 us; speedup vs baseline: 14.3400x; 1.5039x over previous
//
#include <hip/hip_runtime.h>

#define NNODES 100000
#define NEDGES 800000
#define NGRAPHS 5000
#define FN 11
#define FE 4
#define H1C 32
#define H2C 16

typedef __bf16 bf16x8 __attribute__((ext_vector_type(8)));
typedef float f32x4 __attribute__((ext_vector_type(4)));

// agg1[n,o] = c1_bias[o] + sum_i x[n,i]*c1_root[i,o]
__global__ __launch_bounds__(256) void k_init1(const float* __restrict__ x,
    const float* __restrict__ root, const float* __restrict__ bias,
    float* __restrict__ agg1) {
  int t = blockIdx.x * 256 + threadIdx.x;
  int n = t >> 5, o = t & 31;
  if (n >= NNODES) return;
  float acc = bias[o];
  #pragma unroll
  for (int i = 0; i < FN; i++) acc += x[n * FN + i] * root[i * H1C + o];
  agg1[n * H1C + o] = acc;
}

// Pre-swizzled bf16 B-fragments for conv1 MFMA.
// Index: ((ot*12 + step)*64 + lane)*8 + j ; q = (lane>>4)*8+j ; o = (lane&15)+ot*16
// step<11 : B = w2[q][step*32+o]   (z-row q = hidden k, step = node-feat i)
// step==11: B = q<11 ? b2[q*32+o] : 0   (bias term, A = zero-padded xs slice)
__global__ __launch_bounds__(256) void k_prepB1(const float* __restrict__ w2,
    const float* __restrict__ b2, __bf16* __restrict__ B1s) {
  int t = blockIdx.x * 256 + threadIdx.x;
  if (t >= 2 * 12 * 64 * 8) return;
  int j = t & 7;
  int lane = (t >> 3) & 63;
  int rest = t >> 9;        // ot*12 + step
  int step = rest % 12;
  int ot = rest / 12;
  int q = (lane >> 4) * 8 + j;
  int o = (lane & 15) + ot * 16;
  float v;
  if (step < 11) v = w2[q * (FN * H1C) + step * H1C + o];
  else v = (q < FN) ? b2[q * H1C + o] : 0.f;
  B1s[t] = (__bf16)v;
}

// conv1 edge pass via MFMA: msg[e,:] = z[e,:]@B1, z[e,i*32+k] = xs[e,i]*h[e,k].
__global__ __launch_bounds__(256) void k_edge1_mfma(
    const float* __restrict__ x, const int* __restrict__ ei,
    const float* __restrict__ ea, const float* __restrict__ w1,
    const float* __restrict__ b1, const __bf16* __restrict__ B1s,
    float* __restrict__ agg1) {
  __shared__ __bf16 Bl[12288];          // 24 KB B-frags
  __shared__ __bf16 h_sl[4][256][8];    // 16 KB h slices, slice-major
  __shared__ __bf16 xs_sl[4][256][8];   // 16 KB xs slices (zero-padded past 11)
  __shared__ int s_dst[256];
  int tid = threadIdx.x;
  {
    const int4* s = (const int4*)B1s;
    int4* d = (int4*)Bl;
    #pragma unroll
    for (int q = 0; q < 12; q++) d[tid + q * 256] = s[tid + q * 256];
  }
  int e = blockIdx.x * 256 + tid;   // NEDGES % 256 == 0
  int src = ei[e];
  s_dst[tid] = ei[NEDGES + e];
  float4 a4 = *reinterpret_cast<const float4*>(ea + e * 4);
  float h[32];
  #pragma unroll
  for (int k = 0; k < 32; k++) {
    float v = b1[k] + a4.x * w1[k] + a4.y * w1[32 + k] + a4.z * w1[64 + k] + a4.w * w1[96 + k];
    h[k] = v > 0.f ? v : 0.f;
  }
  #pragma unroll
  for (int s = 0; s < 4; s++) {
    bf16x8 t8;
    #pragma unroll
    for (int j = 0; j < 8; j++) t8[j] = (__bf16)h[s * 8 + j];
    *reinterpret_cast<bf16x8*>(&h_sl[s][tid][0]) = t8;
  }
  float xsv[FN];
  #pragma unroll
  for (int i = 0; i < FN; i++) xsv[i] = x[src * FN + i];
  #pragma unroll
  for (int s = 0; s < 4; s++) {
    bf16x8 t8;
    #pragma unroll
    for (int j = 0; j < 8; j++) {
      int k = s * 8 + j;
      t8[j] = (k < FN) ? (__bf16)xsv[k] : (__bf16)0.f;
    }
    *reinterpret_cast<bf16x8*>(&xs_sl[s][tid][0]) = t8;
  }
  __syncthreads();
  int lane = tid & 63;
  int w = tid >> 6;
  int halfk = lane >> 4;
  int er = lane & 15;
  #pragma unroll 1
  for (int g = 0; g < 4; g++) {
    int eb = w * 64 + g * 16;
    int el = eb + er;
    bf16x8 hs8 = *reinterpret_cast<const bf16x8*>(&h_sl[halfk][el][0]);
    bf16x8 xs8 = *reinterpret_cast<const bf16x8*>(&xs_sl[halfk][el][0]);
    float hsf[8];
    #pragma unroll
    for (int j = 0; j < 8; j++) hsf[j] = (float)hs8[j];
    f32x4 acc0 = {0.f, 0.f, 0.f, 0.f};
    f32x4 acc1 = {0.f, 0.f, 0.f, 0.f};
    // bias step (step 11): A = padded xs slice
    {
      bf16x8 b0 = *reinterpret_cast<const bf16x8*>(&Bl[11 * 512 + lane * 8]);
      bf16x8 b1f = *reinterpret_cast<const bf16x8*>(&Bl[6144 + 11 * 512 + lane * 8]);
      acc0 = __builtin_amdgcn_mfma_f32_16x16x32_bf16(xs8, b0, acc0, 0, 0, 0);
      acc1 = __builtin_amdgcn_mfma_f32_16x16x32_bf16(xs8, b1f, acc1, 0, 0, 0);
    }
    #pragma unroll
    for (int i = 0; i < FN; i++) {
      float xscal = (float)xs_sl[i >> 3][el][i & 7];
      bf16x8 af;
      #pragma unroll
      for (int j = 0; j < 8; j++) af[j] = (__bf16)(xscal * hsf[j]);
      bf16x8 b0 = *reinterpret_cast<const bf16x8*>(&Bl[i * 512 + lane * 8]);
      bf16x8 b1f = *reinterpret_cast<const bf16x8*>(&Bl[6144 + i * 512 + lane * 8]);
      acc0 = __builtin_amdgcn_mfma_f32_16x16x32_bf16(af, b0, acc0, 0, 0, 0);
      acc1 = __builtin_amdgcn_mfma_f32_16x16x32_bf16(af, b1f, acc1, 0, 0, 0);
    }
    #pragma unroll
    for (int r = 0; r < 4; r++) {
      int d = s_dst[eb + halfk * 4 + r];
      atomicAdd(&agg1[d * H1C + er], acc0[r]);
      atomicAdd(&agg1[d * H1C + er + 16], acc1[r]);
    }
  }
}

// h1b = bf16(relu(agg1)); agg2[n,o] = c2_bias[o] + sum_i relu(agg1)[n,i]*c2_root[i,o]
__global__ __launch_bounds__(256) void k_mid(const float* __restrict__ agg1,
    const float* __restrict__ root2, const float* __restrict__ bias2,
    __bf16* __restrict__ h1b, float* __restrict__ agg2) {
  int t = blockIdx.x * 256 + threadIdx.x;
  int n = t >> 4, o = t & 15;
  if (n >= NNODES) return;
  float hv[32];
  #pragma unroll
  for (int i = 0; i < 32; i++) {
    float v = agg1[n * H1C + i];
    hv[i] = v > 0.f ? v : 0.f;
  }
  h1b[n * H1C + o] = (__bf16)hv[o];
  h1b[n * H1C + o + 16] = (__bf16)hv[o + 16];
  float acc = bias2[o];
  #pragma unroll
  for (int i = 0; i < 32; i++) acc += hv[i] * root2[i * H2C + o];
  agg2[n * H2C + o] = acc;
}

// Pre-swizzled bf16 B-fragments for conv2 MFMA.
__global__ __launch_bounds__(256) void k_prepB2(const float* __restrict__ w2,
    __bf16* __restrict__ B2s) {
  int t = blockIdx.x * 256 + threadIdx.x;
  if (t >= 32 * 64 * 8) return;
  int kk = t >> 9;
  int l = (t >> 3) & 63;
  int j = t & 7;
  int i = (l >> 4) * 8 + j;
  int o = l & 15;
  B2s[t] = (__bf16)w2[(kk * 32 + i) * H2C + o];
}

// conv2 edge pass via MFMA (verified round 4).
__global__ __launch_bounds__(256) void k_edge2_mfma(
    const __bf16* __restrict__ h1b, const int* __restrict__ ei,
    const float* __restrict__ ea, const float* __restrict__ w1,
    const float* __restrict__ b1, const __bf16* __restrict__ B2s,
    float* __restrict__ agg2) {
  __shared__ __bf16 Bl[32 * 64 * 8];
  __shared__ float h_lds[256][33];
  __shared__ int s_src[256];
  __shared__ int s_dst[256];
  int tid = threadIdx.x;
  {
    const int4* s = (const int4*)B2s;
    int4* d = (int4*)Bl;
    #pragma unroll
    for (int q = 0; q < 8; q++) d[tid * 8 + q] = s[tid * 8 + q];
  }
  int e = blockIdx.x * 256 + tid;
  s_src[tid] = ei[e];
  s_dst[tid] = ei[NEDGES + e];
  float4 a4 = *reinterpret_cast<const float4*>(ea + e * 4);
  #pragma unroll
  for (int k = 0; k < 32; k++) {
    float v = b1[k] + a4.x * w1[k] + a4.y * w1[32 + k] + a4.z * w1[64 + k] + a4.w * w1[96 + k];
    h_lds[tid][k] = v > 0.f ? v : 0.f;
  }
  __syncthreads();
  int lane = tid & 63;
  int w = tid >> 6;
  int halfk = lane >> 4;
  int er = lane & 15;
  #pragma unroll 1
  for (int g = 0; g < 4; g++) {
    int eb = w * 64 + g * 16;
    int el = eb + er;
    int sn = s_src[el];
    bf16x8 hsb = *reinterpret_cast<const bf16x8*>(h1b + sn * H1C + halfk * 8);
    float hsf[8];
    #pragma unroll
    for (int j = 0; j < 8; j++) hsf[j] = (float)hsb[j];
    f32x4 acc = {0.f, 0.f, 0.f, 0.f};
    #pragma unroll
    for (int kk = 0; kk < 32; kk++) {
      float hscal = h_lds[el][kk];
      bf16x8 bfrag = *reinterpret_cast<const bf16x8*>(Bl + (kk * 64 + lane) * 8);
      bf16x8 afrag;
      #pragma unroll
      for (int j = 0; j < 8; j++) afrag[j] = (__bf16)(hscal * hsf[j]);
      acc = __builtin_amdgcn_mfma_f32_16x16x32_bf16(afrag, bfrag, acc, 0, 0, 0);
    }
    #pragma unroll
    for (int r = 0; r < 4; r++) {
      int row = halfk * 4 + r;
      int d = s_dst[eb + row];
      atomicAdd(&agg2[d * H2C + er], acc[r]);
    }
  }
}

// pooled[batch[n],o] += relu(agg2[n,o])
__global__ __launch_bounds__(256) void k_pool(const float* __restrict__ agg2,
    const int* __restrict__ batch, float* __restrict__ pooled) {
  int t = blockIdx.x * 256 + threadIdx.x;
  int n = t >> 4, o = t & 15;
  if (n >= NNODES) return;
  float v = agg2[n * H2C + o];
  v = v > 0.f ? v : 0.f;
  atomicAdd(&pooled[batch[n] * H2C + o], v);
}

// out[g] = relu(pooled[g]@fc1_w + fc1_b) @ out_w + out_b
__global__ __launch_bounds__(256) void k_head(const float* __restrict__ pooled,
    const float* __restrict__ fc1w, const float* __restrict__ fc1b,
    const float* __restrict__ outw, const float* __restrict__ outb,
    float* __restrict__ out) {
  int g = blockIdx.x * 256 + threadIdx.x;
  if (g >= NGRAPHS) return;
  float p[H2C];
  #pragma unroll
  for (int i = 0; i < H2C; i++) p[i] = pooled[g * H2C + i];
  float acc = outb[0];
  #pragma unroll
  for (int o = 0; o < H1C; o++) {
    float v = fc1b[o];
    #pragma unroll
    for (int i = 0; i < H2C; i++) v += p[i] * fc1w[i * H1C + o];
    v = v > 0.f ? v : 0.f;
    acc += v * outw[o];
  }
  out[g] = acc;
}

extern "C" void kernel_launch(void* const* d_in, const int* in_sizes, int n_in,
                              void* d_out, int out_size, void* d_ws, size_t ws_size,
                              hipStream_t stream) {
  const float* x      = (const float*)d_in[0];
  const int*   ei     = (const int*)d_in[1];
  const float* ea     = (const float*)d_in[2];
  const int*   batch  = (const int*)d_in[3];
  const float* c1w1   = (const float*)d_in[4];
  const float* c1b1   = (const float*)d_in[5];
  const float* c1w2   = (const float*)d_in[6];
  const float* c1b2   = (const float*)d_in[7];
  const float* c1root = (const float*)d_in[8];
  const float* c1bias = (const float*)d_in[9];
  const float* c2w1   = (const float*)d_in[10];
  const float* c2b1   = (const float*)d_in[11];
  const float* c2w2   = (const float*)d_in[12];
  const float* c2b2   = (const float*)d_in[13];
  const float* c2root = (const float*)d_in[14];
  const float* c2bias = (const float*)d_in[15];
  const float* fc1w   = (const float*)d_in[16];
  const float* fc1b   = (const float*)d_in[17];
  const float* outw   = (const float*)d_in[18];
  const float* outb   = (const float*)d_in[19];
  float* out = (float*)d_out;

  float*   agg1   = (float*)d_ws;                       // 100000*32 f32
  __bf16*  h1b    = (__bf16*)(agg1 + NNODES * H1C);     // 100000*32 bf16
  float*   agg2   = (float*)(h1b + NNODES * H1C);       // 100000*16 f32
  float*   pooled = agg2 + NNODES * H2C;                // 5000*16 f32
  __bf16*  B2s    = (__bf16*)(pooled + NGRAPHS * H2C);  // 16384 bf16
  __bf16*  B1s    = B2s + 32 * 64 * 8;                  // 12288 bf16

  hipMemsetAsync(pooled, 0, NGRAPHS * H2C * sizeof(float), stream);

  k_init1<<<(NNODES * H1C + 255) / 256, 256, 0, stream>>>(x, c1root, c1bias, agg1);
  k_prepB1<<<48, 256, 0, stream>>>(c1w2, c1b2, B1s);
  k_prepB2<<<64, 256, 0, stream>>>(c2w2, B2s);
  k_edge1_mfma<<<NEDGES / 256, 256, 0, stream>>>(x, ei, ea, c1w1, c1b1, B1s, agg1);
  k_mid<<<(NNODES * H2C + 255) / 256, 256, 0, stream>>>(agg1, c2root, c2bias, h1b, agg2);
  k_edge2_mfma<<<NEDGES / 256, 256, 0, stream>>>(h1b, ei, ea, c2w1, c2b1, B2s, agg2);
  k_pool<<<(NNODES * H2C + 255) / 256, 256, 0, stream>>>(agg2, batch, pooled);
  k_head<<<(NGRAPHS + 255) / 256, 256, 0, stream>>>(pooled, fc1w, fc1b, outw, outb, out);
}